// Round 2
// baseline (9498.199 us; speedup 1.0000x reference)
//
#include <hip/hip_runtime.h>
#include <stdint.h>

typedef unsigned short u16;
typedef short bf16x8 __attribute__((ext_vector_type(8)));
typedef float f32x4 __attribute__((ext_vector_type(4)));

#define DEV __device__ __forceinline__

DEV float bf2f(u16 u){ union{uint32_t i; float f;} v; v.i = ((uint32_t)u)<<16; return v.f; }
DEV u16 f2bf(float f){ union{float f; uint32_t i;} v; v.f=f; uint32_t u=v.i; u += 0x7FFFu + ((u>>16)&1u); return (u16)(u>>16); }
DEV float fast_tanh(float x){ float t=__builtin_amdgcn_exp2f(x*2.885390081777927f); return 1.f-2.f*__builtin_amdgcn_rcpf(t+1.f); }
DEV float fast_sigmoid(float x){ return __builtin_amdgcn_rcpf(1.f+__builtin_amdgcn_exp2f(-1.4426950408889634f*x)); }
DEV f32x4 mfma16(bf16x8 a, bf16x8 b, f32x4 c){ return __builtin_amdgcn_mfma_f32_16x16x32_bf16(a,b,c,0,0,0); }
DEV void atomAddF(float* p, float v){ __hip_atomic_fetch_add(p, v, __ATOMIC_RELAXED, __HIP_MEMORY_SCOPE_AGENT); }

// diagnostic: encode failure cause in d_out so absmax reveals it
__global__ void diag_kernel(float* out, float v){ if (threadIdx.x < 8) out[threadIdx.x] = v; }

// Transpose + bf16-cast + XOR-swizzle a [K][Nn] f32 weight (row stride ld) into
// dst as BT[n][k] bf16 with u16 index (n*K+k)^((n&7)<<3)  (byte ^= (n&7)<<4).
__global__ __launch_bounds__(256) void prep_wT(const float* __restrict__ src, int ld,
                                               u16* __restrict__ dst, int K, int Nn)
{
    int idx = blockIdx.x*256 + threadIdx.x;
    if (idx >= K*Nn) return;
    int n = idx / K, k = idx - n*K;
    dst[(n*K + k) ^ ((n&7)<<3)] = f2bf(src[(size_t)k*ld + n]);
}

// node encoder: rows x 3 -> relu(@w1+b1) -> @w2+b2 -> LN -> h (f32)
__global__ __launch_bounds__(256) void enc_kernel(
    const float* __restrict__ in3, int rows,
    const float* __restrict__ w1, const float* __restrict__ b1,
    const u16* __restrict__ w2T, const float* __restrict__ b2,
    const float* __restrict__ gam, const float* __restrict__ bet,
    float* __restrict__ outF)
{
    __shared__ u16 wbs[128*128];   // 32KB W2^T swizzled
    __shared__ u16 hid[64*128];    // 16KB hidden swizzled
    int tid = threadIdx.x, r0 = blockIdx.x*64;
    for (int i = tid; i < 8192; i += 256) ((uint32_t*)wbs)[i] = ((const uint32_t*)w2T)[i];
    for (int idx = tid; idx < 8192; idx += 256) {
        int r = idx >> 7, c = idx & 127;
        int row = r0 + r; if (row > rows-1) row = rows-1;
        float v = b1[c] + in3[(size_t)row*3+0]*w1[c] + in3[(size_t)row*3+1]*w1[128+c] + in3[(size_t)row*3+2]*w1[256+c];
        hid[idx ^ ((r&7)<<3)] = f2bf(fmaxf(v, 0.f));
    }
    __syncthreads();
    int lane = tid & 63, w = tid >> 6, l16 = lane & 15, q = lane >> 4;
    int ar = 16*w + l16;
    f32x4 acc[8];
    #pragma unroll
    for (int nt=0; nt<8; nt++) acc[nt] = (f32x4){0.f,0.f,0.f,0.f};
    #pragma unroll
    for (int ks=0; ks<4; ks++) {
        bf16x8 af = *(const bf16x8*)&hid[(ar*128 + ks*32 + q*8) ^ ((ar&7)<<3)];
        #pragma unroll
        for (int nt=0; nt<8; nt++) {
            int n = nt*16 + l16;
            bf16x8 bfr = *(const bf16x8*)&wbs[(n*128 + ks*32 + q*8) ^ ((n&7)<<3)];
            acc[nt] = mfma16(af, bfr, acc[nt]);
        }
    }
    float b2v[8], gv[8], bv[8];
    #pragma unroll
    for (int nt=0; nt<8; nt++){ int c = nt*16+l16; b2v[nt]=b2[c]; gv[nt]=gam[c]; bv[nt]=bet[c]; }
    #pragma unroll
    for (int reg=0; reg<4; reg++) {
        float s=0.f, ss=0.f;
        #pragma unroll
        for (int nt=0; nt<8; nt++){ float v = acc[nt][reg] + b2v[nt]; acc[nt][reg]=v; s+=v; ss+=v*v; }
        #pragma unroll
        for (int m=1; m<16; m<<=1){ s += __shfl_xor(s,m); ss += __shfl_xor(ss,m); }
        float mean = s * (1.f/128.f);
        float rstd = __builtin_amdgcn_rsqf(ss*(1.f/128.f) - mean*mean + 1e-5f);
        int row = r0 + 16*w + 4*q + reg;
        if (row < rows) {
            #pragma unroll
            for (int nt=0; nt<8; nt++){
                int c = nt*16+l16;
                outF[(size_t)row*128 + c] = (acc[nt][reg]-mean)*rstd*gv[nt] + bv[nt];
            }
        }
    }
}

// per-64-edge block: recompute e-tile (edge encoder), then msg = relu(h[src]+e),
// atomicAdd into agg[dst]
__global__ __launch_bounds__(256) void msg_rc(
    const float* __restrict__ ea,
    const float* __restrict__ ew1, const float* __restrict__ eb1,
    const u16* __restrict__ ew2T, const float* __restrict__ eb2,
    const float* __restrict__ eg, const float* __restrict__ ebe,
    const float* __restrict__ h,
    const int* __restrict__ src, const int* __restrict__ dst,
    float* __restrict__ agg, int E)
{
    __shared__ u16 wbs[128*128];   // 32KB
    __shared__ u16 hid[64*128];    // 16KB: hidden (swizzled), then e-tile (plain)
    __shared__ float eas[192];
    __shared__ int sIdx[64], dIdx[64];
    int tid = threadIdx.x, r0 = blockIdx.x*64;
    for (int i = tid; i < 8192; i += 256) ((uint32_t*)wbs)[i] = ((const uint32_t*)ew2T)[i];
    if (tid < 192){ int rr = r0 + tid/3; int rc = rr < E ? rr : E-1; eas[tid] = ea[(size_t)rc*3 + (tid - (tid/3)*3)]; }
    else if (tid < 256){ int t = tid-192; int rr = r0+t; int rc = rr<E?rr:E-1; sIdx[t]=src[rc]; dIdx[t]=dst[rc]; }
    __syncthreads();
    for (int idx = tid; idx < 8192; idx += 256){
        int r = idx >> 7, c = idx & 127;
        float v = eb1[c] + eas[r*3]*ew1[c] + eas[r*3+1]*ew1[128+c] + eas[r*3+2]*ew1[256+c];
        hid[idx ^ ((r&7)<<3)] = f2bf(fmaxf(v, 0.f));
    }
    __syncthreads();
    int lane = tid&63, w = tid>>6, l16 = lane&15, q = lane>>4;
    int ar = 16*w + l16;
    f32x4 acc[8];
    #pragma unroll
    for (int nt=0; nt<8; nt++) acc[nt] = (f32x4){0.f,0.f,0.f,0.f};
    #pragma unroll
    for (int ks=0; ks<4; ks++){
        bf16x8 af = *(const bf16x8*)&hid[(ar*128 + ks*32 + q*8) ^ ((ar&7)<<3)];
        #pragma unroll
        for (int nt=0; nt<8; nt++){
            int n = nt*16 + l16;
            bf16x8 bfr = *(const bf16x8*)&wbs[(n*128 + ks*32 + q*8) ^ ((n&7)<<3)];
            acc[nt] = mfma16(af, bfr, acc[nt]);
        }
    }
    __syncthreads();   // all hidden reads done; safe to overwrite hid with e-tile
    {
        float b2v[8], gv[8], bv[8];
        #pragma unroll
        for (int nt=0; nt<8; nt++){ int c = nt*16+l16; b2v[nt]=eb2[c]; gv[nt]=eg[c]; bv[nt]=ebe[c]; }
        #pragma unroll
        for (int reg=0; reg<4; reg++){
            float s=0.f, ss=0.f;
            #pragma unroll
            for (int nt=0; nt<8; nt++){ float v = acc[nt][reg] + b2v[nt]; acc[nt][reg]=v; s+=v; ss+=v*v; }
            #pragma unroll
            for (int m=1; m<16; m<<=1){ s += __shfl_xor(s,m); ss += __shfl_xor(ss,m); }
            float mean = s*(1.f/128.f);
            float rstd = __builtin_amdgcn_rsqf(ss*(1.f/128.f)-mean*mean+1e-5f);
            int rl = 16*w + 4*q + reg;   // full tile row (bugfix: include 16*w)
            #pragma unroll
            for (int nt=0; nt<8; nt++){
                int c = nt*16+l16;
                hid[rl*128 + c] = f2bf((acc[nt][reg]-mean)*rstd*gv[nt] + bv[nt]);  // plain layout
            }
        }
    }
    __syncthreads();
    // message + scatter
    for (int t = tid; t < 2048; t += 256){
        int r = t >> 5, cg = (t & 31) << 2;
        if (r0 + r >= E) continue;
        int s = sIdx[r], d = dIdx[r];
        uint2 ev = *(const uint2*)&hid[r*128 + cg];
        float4 hv = *(const float4*)(h + (size_t)s*128 + cg);
        float m0 = fmaxf(hv.x + bf2f((u16)(ev.x & 0xFFFF)), 0.f);
        float m1 = fmaxf(hv.y + bf2f((u16)(ev.x >> 16)),   0.f);
        float m2 = fmaxf(hv.z + bf2f((u16)(ev.y & 0xFFFF)), 0.f);
        float m3 = fmaxf(hv.w + bf2f((u16)(ev.y >> 16)),   0.f);
        float* ap = agg + (size_t)d*128 + cg;
        atomAddF(ap+0, m0); atomAddF(ap+1, m1); atomAddF(ap+2, m2); atomAddF(ap+3, m3);
    }
}

// z=(1+eps)h+agg; h = LN(relu(z@W1+b1)@W2+b2) [+relu] in-place
__global__ __launch_bounds__(256) void gine_update(
    float* h, const float* __restrict__ agg,
    const float* __restrict__ epsArr, int layer,
    const u16* __restrict__ w1T, const u16* __restrict__ w2T,
    const float* __restrict__ b1, const float* __restrict__ b2,
    const float* __restrict__ gam, const float* __restrict__ bet,
    int rows, int doRelu)
{
    __shared__ u16 wbs[128*128];
    __shared__ u16 hid[64*128];
    int tid = threadIdx.x, r0 = blockIdx.x*64;
    float epsv = 1.f + epsArr[layer];
    for (int i = tid; i < 8192; i += 256) ((uint32_t*)wbs)[i] = ((const uint32_t*)w1T)[i];
    __syncthreads();
    int lane = tid&63, w = tid>>6, l16 = lane&15, q = lane>>4;
    int ar = 16*w + l16;
    int arow = r0 + ar;
    int arc = arow < rows ? arow : rows-1;
    f32x4 acc[8];
    #pragma unroll
    for (int nt=0; nt<8; nt++) acc[nt] = (f32x4){0.f,0.f,0.f,0.f};
    #pragma unroll
    for (int ks=0; ks<4; ks++){
        const float4* hp = (const float4*)(h   + (size_t)arc*128 + ks*32 + q*8);
        const float4* ap = (const float4*)(agg + (size_t)arc*128 + ks*32 + q*8);
        float4 h0 = hp[0], h1 = hp[1], a0 = ap[0], a1 = ap[1];
        bf16x8 af;
        af[0]=(short)f2bf(fmaf(epsv,h0.x,a0.x)); af[1]=(short)f2bf(fmaf(epsv,h0.y,a0.y));
        af[2]=(short)f2bf(fmaf(epsv,h0.z,a0.z)); af[3]=(short)f2bf(fmaf(epsv,h0.w,a0.w));
        af[4]=(short)f2bf(fmaf(epsv,h1.x,a1.x)); af[5]=(short)f2bf(fmaf(epsv,h1.y,a1.y));
        af[6]=(short)f2bf(fmaf(epsv,h1.z,a1.z)); af[7]=(short)f2bf(fmaf(epsv,h1.w,a1.w));
        #pragma unroll
        for (int nt=0; nt<8; nt++){
            int n = nt*16 + l16;
            bf16x8 bfr = *(const bf16x8*)&wbs[(n*128 + ks*32 + q*8) ^ ((n&7)<<3)];
            acc[nt] = mfma16(af, bfr, acc[nt]);
        }
    }
    #pragma unroll
    for (int nt=0; nt<8; nt++){
        int c = nt*16 + l16; float b1v = b1[c];
        #pragma unroll
        for (int reg=0; reg<4; reg++){
            int rl = 16*w + 4*q + reg;   // bugfix: include 16*w
            hid[(rl*128 + c) ^ ((rl&7)<<3)] = f2bf(fmaxf(acc[nt][reg] + b1v, 0.f));
        }
    }
    __syncthreads();
    for (int i = tid; i < 8192; i += 256) ((uint32_t*)wbs)[i] = ((const uint32_t*)w2T)[i];
    __syncthreads();
    f32x4 a2[8];
    #pragma unroll
    for (int nt=0; nt<8; nt++) a2[nt] = (f32x4){0.f,0.f,0.f,0.f};
    #pragma unroll
    for (int ks=0; ks<4; ks++){
        bf16x8 af = *(const bf16x8*)&hid[(ar*128 + ks*32 + q*8) ^ ((ar&7)<<3)];
        #pragma unroll
        for (int nt=0; nt<8; nt++){
            int n = nt*16 + l16;
            bf16x8 bfr = *(const bf16x8*)&wbs[(n*128 + ks*32 + q*8) ^ ((n&7)<<3)];
            a2[nt] = mfma16(af, bfr, a2[nt]);
        }
    }
    float b2v[8], gv[8], bv[8];
    #pragma unroll
    for (int nt=0; nt<8; nt++){ int c = nt*16+l16; b2v[nt]=b2[c]; gv[nt]=gam[c]; bv[nt]=bet[c]; }
    #pragma unroll
    for (int reg=0; reg<4; reg++){
        float s=0.f, ss=0.f;
        #pragma unroll
        for (int nt=0; nt<8; nt++){ float v = a2[nt][reg] + b2v[nt]; a2[nt][reg]=v; s+=v; ss+=v*v; }
        #pragma unroll
        for (int m=1; m<16; m<<=1){ s += __shfl_xor(s,m); ss += __shfl_xor(ss,m); }
        float mean = s*(1.f/128.f);
        float rstd = __builtin_amdgcn_rsqf(ss*(1.f/128.f)-mean*mean+1e-5f);
        int row = r0 + 16*w + 4*q + reg;
        if (row < rows){
            #pragma unroll
            for (int nt=0; nt<8; nt++){
                int c = nt*16+l16;
                float o = (a2[nt][reg]-mean)*rstd*gv[nt] + bv[nt];
                if (doRelu) o = fmaxf(o, 0.f);
                h[(size_t)row*128 + c] = o;
            }
        }
    }
}

__global__ __launch_bounds__(256) void pool_kernel(
    const float* __restrict__ h, const int* __restrict__ batch,
    float* __restrict__ gsum, float* __restrict__ cnt, int N)
{
    int idx = blockIdx.x*256 + threadIdx.x;
    int n = idx >> 5, cg = (idx & 31) << 2;
    if (n >= N) return;
    int b = batch[n];
    float4 hv = *(const float4*)(h + (size_t)n*128 + cg);
    float* gp = gsum + b*128 + cg;
    atomAddF(gp+0, hv.x); atomAddF(gp+1, hv.y); atomAddF(gp+2, hv.z); atomAddF(gp+3, hv.w);
    if (cg == 0) atomAddF(cnt + b, 1.f);
}

__global__ __launch_bounds__(256) void gproc_kernel(
    const float* __restrict__ gsum, const float* __restrict__ cnt,
    const float* __restrict__ gw, const float* __restrict__ gb,
    const float* __restrict__ gg, const float* __restrict__ gbe,
    float* __restrict__ gfin)
{
    __shared__ float gm[2048];
    int tid = threadIdx.x;
    for (int i = tid; i < 2048; i += 256){ int b = i >> 7; gm[i] = gsum[i] / fmaxf(cnt[b], 1.f); }
    __syncthreads();
    int r = tid >> 4, m = tid & 15;
    float a[8];
    #pragma unroll
    for (int j=0;j<8;j++) a[j]=0.f;
    for (int k=0;k<128;k++){
        float gv = gm[r*128+k];
        #pragma unroll
        for (int j=0;j<8;j++) a[j] = fmaf(gv, gw[k*128 + m + 16*j], a[j]);
    }
    float s=0.f, ss=0.f;
    #pragma unroll
    for (int j=0;j<8;j++){ float v = fmaxf(a[j] + gb[m+16*j], 0.f); a[j]=v; s+=v; ss+=v*v; }
    #pragma unroll
    for (int msk=1; msk<16; msk<<=1){ s += __shfl_xor(s,msk); ss += __shfl_xor(ss,msk); }
    float mean = s*(1.f/128.f);
    float rstd = __builtin_amdgcn_rsqf(ss*(1.f/128.f)-mean*mean+1e-5f);
    #pragma unroll
    for (int j=0;j<8;j++){ int c = m+16*j; gfin[r*128+c] = (a[j]-mean)*rstd*gg[c] + gbe[c]; }
}

// Gc[16][256] = gfin @ W1c + ep_b1   (W1c = ep_w1 rows 256..383)
__global__ __launch_bounds__(256) void gc_kernel(
    const float* __restrict__ gfin, const float* __restrict__ ep_w1,
    const float* __restrict__ ep_b1, float* __restrict__ Gc)
{
    __shared__ float gs[2048];
    int tid = threadIdx.x;
    for (int i = tid; i < 2048; i += 256) gs[i] = gfin[i];
    __syncthreads();
    for (int o = tid; o < 16*256; o += 256){
        int r = o >> 8, n = o & 255;
        float a = ep_b1[n];
        for (int k = 0; k < 128; k++) a = fmaf(gs[r*128+k], ep_w1[(size_t)(256+k)*256 + n], a);
        Gc[o] = a;
    }
}

// HcS = h @ W1a, HcD = h @ W1b (bf16 [N][256]); 32KB weight chunks
__global__ __launch_bounds__(256) void hc_prep(
    const float* __restrict__ h, const u16* __restrict__ w1aT, const u16* __restrict__ w1bT,
    u16* __restrict__ hcS, u16* __restrict__ hcD, int rows)
{
    __shared__ u16 wbs[128*128]; // 32KB
    int tid = threadIdx.x, r0 = blockIdx.x*64;
    int lane = tid&63, w = tid>>6, l16 = lane&15, q = lane>>4;
    int arow = r0 + 16*w + l16;
    int arc = arow < rows ? arow : rows-1;
    bf16x8 afk[4];
    #pragma unroll
    for (int ks=0; ks<4; ks++){
        const float4* hp = (const float4*)(h + (size_t)arc*128 + ks*32 + q*8);
        float4 h0 = hp[0], h1 = hp[1];
        bf16x8 af;
        af[0]=(short)f2bf(h0.x); af[1]=(short)f2bf(h0.y); af[2]=(short)f2bf(h0.z); af[3]=(short)f2bf(h0.w);
        af[4]=(short)f2bf(h1.x); af[5]=(short)f2bf(h1.y); af[6]=(short)f2bf(h1.z); af[7]=(short)f2bf(h1.w);
        afk[ks] = af;
    }
    #pragma unroll
    for (int pass = 0; pass < 2; pass++){
        const u16* wt = pass ? w1bT : w1aT;
        f32x4 acc[16];
        #pragma unroll
        for (int i=0; i<16; i++) acc[i] = (f32x4){0.f,0.f,0.f,0.f};
        #pragma unroll
        for (int ch = 0; ch < 2; ch++){
            __syncthreads();
            for (int i = tid; i < 8192; i += 256) ((uint32_t*)wbs)[i] = ((const uint32_t*)wt)[ch*8192 + i];
            __syncthreads();
            #pragma unroll
            for (int ks=0; ks<4; ks++){
                #pragma unroll
                for (int nt=0; nt<8; nt++){
                    int n = nt*16 + l16;
                    bf16x8 bfr = *(const bf16x8*)&wbs[(n*128 + ks*32 + q*8) ^ ((n&7)<<3)];
                    acc[ch*8+nt] = mfma16(afk[ks], bfr, acc[ch*8+nt]);
                }
            }
        }
        u16* outp = pass ? hcD : hcS;
        #pragma unroll
        for (int reg=0; reg<4; reg++){
            int row = r0 + 16*w + 4*q + reg;
            if (row < rows){
                #pragma unroll
                for (int i=0; i<16; i++) outp[(size_t)row*256 + i*16 + l16] = f2bf(acc[i][reg]);
            }
        }
    }
}

// full edge predictor with recomputed e-tile; LDS = 16K wbs + 32K s1t (het aliased) + eas
__global__ __launch_bounds__(256) void pred_rc(
    const float* __restrict__ ea,
    const float* __restrict__ ew1, const float* __restrict__ eb1,
    const u16* __restrict__ ew2T, const float* __restrict__ eb2,
    const float* __restrict__ eg, const float* __restrict__ ebe,
    const int* __restrict__ src, const int* __restrict__ dst, const int* __restrict__ batch,
    const u16* __restrict__ hcS, const u16* __restrict__ hcD, const float* __restrict__ Gc,
    const u16* __restrict__ w1dT, const u16* __restrict__ epw2T,
    const float* __restrict__ b2, const float* __restrict__ w3, const float* __restrict__ b3,
    float* __restrict__ out, int E)
{
    __shared__ u16 wbs[64*128];   // 16KB weight chunk
    __shared__ u16 s1t[64*256];   // 32KB; first 16KB doubles as het (hidden/e-tile)
    __shared__ float eas[192];
    u16* het = s1t;
    int tid = threadIdx.x, r0 = blockIdx.x*64;
    int lane = tid&63, w = tid>>6, l16 = lane&15, q = lane>>4;
    int ar = 16*w + l16;

    if (tid < 192){ int rr = r0 + tid/3; int rc = rr < E ? rr : E-1; eas[tid] = ea[(size_t)rc*3 + (tid - (tid/3)*3)]; }
    int er[4], s4[4], d4[4], g4[4];
    #pragma unroll
    for (int reg=0; reg<4; reg++){
        int r = r0 + 16*w + 4*q + reg; er[reg] = r;
        int rc = r < E ? r : E-1;
        s4[reg] = src[rc]; d4[reg] = dst[rc]; g4[reg] = batch[s4[reg]];
    }
    __syncthreads();
    // encoder hidden
    for (int idx = tid; idx < 8192; idx += 256){
        int r = idx >> 7, c = idx & 127;
        float v = eb1[c] + eas[r*3]*ew1[c] + eas[r*3+1]*ew1[128+c] + eas[r*3+2]*ew1[256+c];
        het[idx ^ ((r&7)<<3)] = f2bf(fmaxf(v, 0.f));
    }
    // encoder GEMM (2 chunks of 64 cols)
    f32x4 eac[8];
    #pragma unroll
    for (int i=0;i<8;i++) eac[i] = (f32x4){0.f,0.f,0.f,0.f};
    #pragma unroll
    for (int ch=0; ch<2; ch++){
        __syncthreads();
        for (int i=tid; i<4096; i+=256) ((uint32_t*)wbs)[i] = ((const uint32_t*)ew2T)[ch*4096 + i];
        __syncthreads();
        #pragma unroll
        for (int ks=0; ks<4; ks++){
            bf16x8 af = *(const bf16x8*)&het[(ar*128 + ks*32 + q*8) ^ ((ar&7)<<3)];
            #pragma unroll
            for (int nt=0; nt<4; nt++){
                int n = nt*16 + l16;
                bf16x8 bfr = *(const bf16x8*)&wbs[(n*128 + ks*32 + q*8) ^ ((n&7)<<3)];
                eac[ch*4+nt] = mfma16(af, bfr, eac[ch*4+nt]);
            }
        }
    }
    __syncthreads();   // all hidden reads done
    // LN -> e-tile back into het (swizzled)
    {
        float b2v[8], gv[8], bv[8];
        #pragma unroll
        for (int i=0;i<8;i++){ int c=i*16+l16; b2v[i]=eb2[c]; gv[i]=eg[c]; bv[i]=ebe[c]; }
        #pragma unroll
        for (int reg=0; reg<4; reg++){
            float s=0.f, ss=0.f;
            #pragma unroll
            for (int i=0;i<8;i++){ float v = eac[i][reg]+b2v[i]; eac[i][reg]=v; s+=v; ss+=v*v; }
            #pragma unroll
            for (int m=1;m<16;m<<=1){ s+=__shfl_xor(s,m); ss+=__shfl_xor(ss,m); }
            float mean = s*(1.f/128.f);
            float rstd = __builtin_amdgcn_rsqf(ss*(1.f/128.f)-mean*mean+1e-5f);
            int rl = 16*w + 4*q + reg;
            #pragma unroll
            for (int i=0;i<8;i++){
                int c = i*16+l16;
                het[(rl*128 + c) ^ ((rl&7)<<3)] = f2bf((eac[i][reg]-mean)*rstd*gv[i]+bv[i]);
            }
        }
    }
    // GEMM1: e @ W1d -> 256 cols, 4 chunks of 64
    f32x4 acc[16];
    #pragma unroll
    for (int i=0;i<16;i++) acc[i] = (f32x4){0.f,0.f,0.f,0.f};
    #pragma unroll
    for (int ch=0; ch<4; ch++){
        __syncthreads();
        for (int i=tid; i<4096; i+=256) ((uint32_t*)wbs)[i] = ((const uint32_t*)w1dT)[ch*4096 + i];
        __syncthreads();
        #pragma unroll
        for (int ks=0; ks<4; ks++){
            bf16x8 af = *(const bf16x8*)&het[(ar*128 + ks*32 + q*8) ^ ((ar&7)<<3)];
            #pragma unroll
            for (int nt=0; nt<4; nt++){
                int n = nt*16 + l16;
                bf16x8 bfr = *(const bf16x8*)&wbs[(n*128 + ks*32 + q*8) ^ ((n&7)<<3)];
                acc[ch*4+nt] = mfma16(af, bfr, acc[ch*4+nt]);
            }
        }
    }
    __syncthreads();   // het reads done -> safe to overwrite s1t region
    // epilogue: add gathers, tanh, write s1t
    #pragma unroll
    for (int i=0; i<16; i++){
        int c = i*16 + l16;
        #pragma unroll
        for (int reg=0; reg<4; reg++){
            float t = acc[i][reg]
                    + bf2f(hcS[(size_t)s4[reg]*256 + c])
                    + bf2f(hcD[(size_t)d4[reg]*256 + c])
                    + Gc[g4[reg]*256 + c];
            int rl = 16*w + 4*q + reg;   // full tile row (bugfix)
            s1t[(rl*256 + c) ^ ((rl&7)<<3)] = f2bf(fast_tanh(t));
        }
    }
    // GEMM2: s1 @ ep_w2 (256->128), chunks over (khalf, nhalf)
    f32x4 a2[8];
    #pragma unroll
    for (int i=0;i<8;i++) a2[i] = (f32x4){0.f,0.f,0.f,0.f};
    #pragma unroll
    for (int kh=0; kh<2; kh++){
        #pragma unroll
        for (int nh=0; nh<2; nh++){
            __syncthreads();
            for (int i=tid; i<4096; i+=256)
                ((uint32_t*)wbs)[i] = ((const uint32_t*)epw2T)[(nh*64 + (i>>6))*128 + kh*64 + (i&63)];
            __syncthreads();
            #pragma unroll
            for (int ks=0; ks<4; ks++){
                bf16x8 af = *(const bf16x8*)&s1t[(ar*256 + kh*128 + ks*32 + q*8) ^ ((ar&7)<<3)];
                #pragma unroll
                for (int nt=0; nt<4; nt++){
                    int nl = nt*16 + l16;
                    bf16x8 bfr = *(const bf16x8*)&wbs[(nl*128 + ks*32 + q*8) ^ ((nl&7)<<3)];
                    a2[nh*4+nt] = mfma16(af, bfr, a2[nh*4+nt]);
                }
            }
        }
    }
    // final: tanh, dot w3, reduce, sigmoid
    float p[4] = {0.f,0.f,0.f,0.f};
    #pragma unroll
    for (int i=0;i<8;i++){
        int c = i*16 + l16;
        float b2v = b2[c], w3v = w3[c];
        #pragma unroll
        for (int reg=0;reg<4;reg++){
            float v = fast_tanh(a2[i][reg] + b2v);
            p[reg] = fmaf(v, w3v, p[reg]);
        }
    }
    float b3v = b3[0];
    #pragma unroll
    for (int reg=0;reg<4;reg++){
        float pv = p[reg];
        #pragma unroll
        for (int m=1;m<16;m<<=1) pv += __shfl_xor(pv,m);
        if (l16==0 && er[reg] < E) out[er[reg]] = fast_sigmoid(pv + b3v);
    }
}

extern "C" void kernel_launch(void* const* d_in, const int* in_sizes, int n_in,
                              void* d_out, int out_size, void* d_ws, size_t ws_size,
                              hipStream_t stream)
{
    if (n_in < 33){ diag_kernel<<<1,64,0,stream>>>((float*)d_out, 2.0e6f); return; }
    const float* x      = (const float*)d_in[0];
    const float* ea     = (const float*)d_in[1];
    const int*   eidx   = (const int*)  d_in[2];
    const int*   batch  = (const int*)  d_in[3];
    const float* ne_w1  = (const float*)d_in[4];
    const float* ne_b1  = (const float*)d_in[5];
    const float* ne_w2  = (const float*)d_in[6];
    const float* ne_b2  = (const float*)d_in[7];
    const float* ne_g   = (const float*)d_in[8];
    const float* ne_be  = (const float*)d_in[9];
    const float* ee_w1  = (const float*)d_in[10];
    const float* ee_b1  = (const float*)d_in[11];
    const float* ee_w2  = (const float*)d_in[12];
    const float* ee_b2  = (const float*)d_in[13];
    const float* ee_g   = (const float*)d_in[14];
    const float* ee_be  = (const float*)d_in[15];
    const float* gin_eps= (const float*)d_in[16];
    const float* gin_w1 = (const float*)d_in[17];
    const float* gin_b1 = (const float*)d_in[18];
    const float* gin_w2 = (const float*)d_in[19];
    const float* gin_b2 = (const float*)d_in[20];
    const float* gin_g  = (const float*)d_in[21];
    const float* gin_be = (const float*)d_in[22];
    const float* gp_w   = (const float*)d_in[23];
    const float* gp_b   = (const float*)d_in[24];
    const float* gp_g   = (const float*)d_in[25];
    const float* gp_be  = (const float*)d_in[26];
    const float* ep_w1  = (const float*)d_in[27];
    const float* ep_b1  = (const float*)d_in[28];
    const float* ep_w2  = (const float*)d_in[29];
    const float* ep_b2  = (const float*)d_in[30];
    const float* ep_w3  = (const float*)d_in[31];
    const float* ep_b3  = (const float*)d_in[32];

    int N = in_sizes[0] / 3;
    int E = in_sizes[1] / 3;
    const int* srcI = eidx;
    const int* dstI = eidx + E;

    char* ws = (char*)d_ws;
    size_t off = 0;
    auto alloc = [&](size_t bytes) -> void* {
        void* p = ws + off; off += (bytes + 255) & ~(size_t)255; return p;
    };
    float* h    = (float*)alloc((size_t)N*512);
    char*  R1   = (char*) alloc((size_t)N*512);   // agg (f32 N*128) then hcS (bf16 N*256)
    u16*   hcD  = (u16*)  alloc((size_t)N*512);
    float* gsum = (float*)alloc((2048+64)*4);
    float* cnt  = gsum + 2048;
    float* gfin = (float*)alloc(2048*4);
    float* Gc   = (float*)alloc(16*256*4);
    u16* ne_w2T = (u16*)alloc(16384*2);
    u16* ee_w2T = (u16*)alloc(16384*2);
    u16* gw1T0  = (u16*)alloc(16384*2);
    u16* gw1T1  = (u16*)alloc(16384*2);
    u16* gw2T0  = (u16*)alloc(16384*2);
    u16* gw2T1  = (u16*)alloc(16384*2);
    u16* w1aT   = (u16*)alloc(32768*2);
    u16* w1bT   = (u16*)alloc(32768*2);
    u16* w1dT   = (u16*)alloc(32768*2);
    u16* epw2T  = (u16*)alloc(32768*2);
    if (off > ws_size){
        diag_kernel<<<1,64,0,stream>>>((float*)d_out, 1.0e6f + (float)(ws_size >> 20));
        return;
    }
    float* agg = (float*)R1;
    u16*   hcS = (u16*)R1;

    prep_wT<<<64, 256, 0, stream>>>(ne_w2, 128, ne_w2T, 128, 128);
    prep_wT<<<64, 256, 0, stream>>>(ee_w2, 128, ee_w2T, 128, 128);
    prep_wT<<<64, 256, 0, stream>>>(gin_w1,           128, gw1T0, 128, 128);
    prep_wT<<<64, 256, 0, stream>>>(gin_w1 + 128*128, 128, gw1T1, 128, 128);
    prep_wT<<<64, 256, 0, stream>>>(gin_w2,           128, gw2T0, 128, 128);
    prep_wT<<<64, 256, 0, stream>>>(gin_w2 + 128*128, 128, gw2T1, 128, 128);
    prep_wT<<<128,256, 0, stream>>>(ep_w1,            256, w1aT, 128, 256);
    prep_wT<<<128,256, 0, stream>>>(ep_w1 + 128*256,  256, w1bT, 128, 256);
    prep_wT<<<128,256, 0, stream>>>(ep_w1 + 384*256,  256, w1dT, 128, 256);
    prep_wT<<<128,256, 0, stream>>>(ep_w2,            128, epw2T, 256, 128);

    int nbN = (N + 63) / 64;
    int nbE = (E + 63) / 64;
    enc_kernel<<<nbN, 256, 0, stream>>>(x, N, ne_w1, ne_b1, ne_w2T, ne_b2, ne_g, ne_be, h);

    for (int l = 0; l < 2; l++){
        hipMemsetAsync(agg, 0, (size_t)N*512, stream);
        msg_rc<<<nbE, 256, 0, stream>>>(ea, ee_w1, ee_b1, ee_w2T, ee_b2, ee_g, ee_be,
                                        h, srcI, dstI, agg, E);
        gine_update<<<nbN, 256, 0, stream>>>(h, agg, gin_eps, l,
            l ? gw1T1 : gw1T0, l ? gw2T1 : gw2T0,
            gin_b1 + l*128, gin_b2 + l*128, gin_g + l*128, gin_be + l*128,
            N, l == 0 ? 1 : 0);
    }

    hipMemsetAsync(gsum, 0, (2048 + 16) * 4, stream);
    pool_kernel<<<(N*32 + 255)/256, 256, 0, stream>>>(h, batch, gsum, cnt, N);
    gproc_kernel<<<1, 256, 0, stream>>>(gsum, cnt, gp_w, gp_b, gp_g, gp_be, gfin);
    gc_kernel<<<1, 256, 0, stream>>>(gfin, ep_w1, ep_b1, Gc);
    hc_prep<<<nbN, 256, 0, stream>>>(h, w1aT, w1bT, hcS, hcD, N);
    pred_rc<<<nbE, 256, 0, stream>>>(ea, ee_w1, ee_b1, ee_w2T, ee_b2, ee_g, ee_be,
                                     srcI, dstI, batch, hcS, hcD, Gc,
                                     w1dT, epw2T, ep_b2, ep_w3, ep_b3,
                                     (float*)d_out, E);
}

// Round 3
// 5353.736 us; speedup vs baseline: 1.7741x; 1.7741x over previous
//
#include <hip/hip_runtime.h>
#include <stdint.h>

typedef unsigned short u16;
typedef short bf16x8 __attribute__((ext_vector_type(8)));
typedef float f32x4 __attribute__((ext_vector_type(4)));

#define DEV __device__ __forceinline__

DEV float bf2f(u16 u){ union{uint32_t i; float f;} v; v.i = ((uint32_t)u)<<16; return v.f; }
DEV u16 f2bf(float f){ union{float f; uint32_t i;} v; v.f=f; uint32_t u=v.i; u += 0x7FFFu + ((u>>16)&1u); return (u16)(u>>16); }
DEV float fast_tanh(float x){ float t=__builtin_amdgcn_exp2f(x*2.885390081777927f); return 1.f-2.f*__builtin_amdgcn_rcpf(t+1.f); }
DEV float fast_sigmoid(float x){ return __builtin_amdgcn_rcpf(1.f+__builtin_amdgcn_exp2f(-1.4426950408889634f*x)); }
DEV f32x4 mfma16(bf16x8 a, bf16x8 b, f32x4 c){ return __builtin_amdgcn_mfma_f32_16x16x32_bf16(a,b,c,0,0,0); }
DEV void atomAddF(float* p, float v){ __hip_atomic_fetch_add(p, v, __ATOMIC_RELAXED, __HIP_MEMORY_SCOPE_AGENT); }

__global__ void diag_kernel(float* out, float v){ if (threadIdx.x < 8) out[threadIdx.x] = v; }

// Transpose + bf16-cast + XOR-swizzle weight [K][Nn] (row stride ld) -> BT[n][k]
__global__ __launch_bounds__(256) void prep_wT(const float* __restrict__ src, int ld,
                                               u16* __restrict__ dst, int K, int Nn)
{
    int idx = blockIdx.x*256 + threadIdx.x;
    if (idx >= K*Nn) return;
    int n = idx / K, k = idx - n*K;
    dst[(n*K + k) ^ ((n&7)<<3)] = f2bf(src[(size_t)k*ld + n]);
}

// ---------------- CSR-by-dst build (counting sort) ----------------
__global__ __launch_bounds__(256) void hist_kernel(const int* __restrict__ dst,
                                                   int* __restrict__ deg, int E)
{
    int e = blockIdx.x*256 + threadIdx.x;
    if (e < E) atomicAdd(&deg[dst[e]], 1);
}

__global__ __launch_bounds__(1024) void scan_kernel(const int* __restrict__ deg,
                                                    int* __restrict__ cur, int N)
{
    __shared__ int sc[1024];
    int t = threadIdx.x;
    int chunk = (N + 1023) / 1024;
    int i0 = t * chunk, i1 = i0 + chunk; if (i1 > N) i1 = N;
    int s = 0;
    for (int i = i0; i < i1; i++) s += deg[i];
    sc[t] = s; __syncthreads();
    int own = s;
    for (int off = 1; off < 1024; off <<= 1){
        int v = (t >= off) ? sc[t - off] : 0;
        __syncthreads();
        sc[t] += v;
        __syncthreads();
    }
    int run = sc[t] - own;   // exclusive prefix
    for (int i = i0; i < i1; i++){ cur[i] = run; run += deg[i]; }
}

__global__ __launch_bounds__(256) void scatter_kernel(
    const int* __restrict__ src, const int* __restrict__ dst, const float* __restrict__ ea,
    int* __restrict__ cur, int* __restrict__ src_s, int* __restrict__ dst_s,
    float* __restrict__ ea_s, int E)
{
    int e = blockIdx.x*256 + threadIdx.x;
    if (e >= E) return;
    int d = dst[e];
    int pos = atomicAdd(&cur[d], 1);
    src_s[pos] = src[e];
    dst_s[pos] = d;
    ea_s[(size_t)pos*3+0] = ea[(size_t)e*3+0];
    ea_s[(size_t)pos*3+1] = ea[(size_t)e*3+1];
    ea_s[(size_t)pos*3+2] = ea[(size_t)e*3+2];
}

// ---------------- node encoder ----------------
__global__ __launch_bounds__(256) void enc_kernel(
    const float* __restrict__ in3, int rows,
    const float* __restrict__ w1, const float* __restrict__ b1,
    const u16* __restrict__ w2T, const float* __restrict__ b2,
    const float* __restrict__ gam, const float* __restrict__ bet,
    float* __restrict__ outF)
{
    __shared__ u16 wbs[128*128];
    __shared__ u16 hid[64*128];
    int tid = threadIdx.x, r0 = blockIdx.x*64;
    for (int i = tid; i < 8192; i += 256) ((uint32_t*)wbs)[i] = ((const uint32_t*)w2T)[i];
    for (int idx = tid; idx < 8192; idx += 256) {
        int r = idx >> 7, c = idx & 127;
        int row = r0 + r; if (row > rows-1) row = rows-1;
        float v = b1[c] + in3[(size_t)row*3+0]*w1[c] + in3[(size_t)row*3+1]*w1[128+c] + in3[(size_t)row*3+2]*w1[256+c];
        hid[idx ^ ((r&7)<<3)] = f2bf(fmaxf(v, 0.f));
    }
    __syncthreads();
    int lane = tid & 63, w = tid >> 6, l16 = lane & 15, q = lane >> 4;
    int ar = 16*w + l16;
    f32x4 acc[8];
    #pragma unroll
    for (int nt=0; nt<8; nt++) acc[nt] = (f32x4){0.f,0.f,0.f,0.f};
    #pragma unroll
    for (int ks=0; ks<4; ks++) {
        bf16x8 af = *(const bf16x8*)&hid[(ar*128 + ks*32 + q*8) ^ ((ar&7)<<3)];
        #pragma unroll
        for (int nt=0; nt<8; nt++) {
            int n = nt*16 + l16;
            bf16x8 bfr = *(const bf16x8*)&wbs[(n*128 + ks*32 + q*8) ^ ((n&7)<<3)];
            acc[nt] = mfma16(af, bfr, acc[nt]);
        }
    }
    float b2v[8], gv[8], bv[8];
    #pragma unroll
    for (int nt=0; nt<8; nt++){ int c = nt*16+l16; b2v[nt]=b2[c]; gv[nt]=gam[c]; bv[nt]=bet[c]; }
    #pragma unroll
    for (int reg=0; reg<4; reg++) {
        float s=0.f, ss=0.f;
        #pragma unroll
        for (int nt=0; nt<8; nt++){ float v = acc[nt][reg] + b2v[nt]; acc[nt][reg]=v; s+=v; ss+=v*v; }
        #pragma unroll
        for (int m=1; m<16; m<<=1){ s += __shfl_xor(s,m); ss += __shfl_xor(ss,m); }
        float mean = s * (1.f/128.f);
        float rstd = __builtin_amdgcn_rsqf(ss*(1.f/128.f) - mean*mean + 1e-5f);
        int row = r0 + 16*w + 4*q + reg;
        if (row < rows) {
            #pragma unroll
            for (int nt=0; nt<8; nt++){
                int c = nt*16+l16;
                outF[(size_t)row*128 + c] = (acc[nt][reg]-mean)*rstd*gv[nt] + bv[nt];
            }
        }
    }
}

// ---------------- dst-sorted message pass ----------------
// per-64-edge block (edges sorted by dst): recompute e-tile (MFMA), msg=relu(h[src]+e),
// segmented LDS reduction by dst run, then plain-store interior rows / atomic boundary rows.
__global__ __launch_bounds__(256) void msg_sorted(
    const float* __restrict__ ea_s, const int* __restrict__ src_s, const int* __restrict__ dst_s,
    const float* __restrict__ ew1, const float* __restrict__ eb1,
    const u16* __restrict__ ew2T, const float* __restrict__ eb2,
    const float* __restrict__ eg, const float* __restrict__ ebe,
    const float* __restrict__ h, float* __restrict__ agg, int E)
{
    __shared__ float lag[8192];    // 32KB: W2^T (as u16) during GEMM, then f32 agg slots
    __shared__ u16 hid[64*128];    // 16KB
    __shared__ float eas[192];
    __shared__ int ssrc[64], sdv[64], sslot[64], sfl[64];
    u16* wbs = (u16*)lag;
    int tid = threadIdx.x, r0 = blockIdx.x*64;

    for (int i = tid; i < 8192; i += 256) ((uint32_t*)lag)[i] = ((const uint32_t*)ew2T)[i];
    if (tid < 192){ int gi = r0*3 + tid; eas[tid] = (gi < E*3) ? ea_s[gi] : 0.f; }
    if (tid < 64){  // wave 0: segmentation metadata
        int r = tid, ge = r0 + r;
        int valid = ge < E;
        int gc = valid ? ge : E-1;
        int dv = dst_s[gc];
        int sv = src_s[gc];
        int pin = __shfl_up(dv, 1);
        int head = (r == 0) || (dv != pin);
        int prevLast  = (r0 > 0)      ? dst_s[r0-1]  : -2;
        int nextFirst = (r0 + 64 < E) ? dst_s[r0+64] : -2;
        int interior = (dv != prevLast) && (dv != nextFirst);
        int s = head ? r : 0;
        #pragma unroll
        for (int off=1; off<64; off<<=1){ int v = __shfl_up(s, off); if (r >= off) s = (s > v ? s : v); }
        ssrc[r]=sv; sdv[r]=dv; sslot[r]=s;
        sfl[r] = ((head && valid)?1:0) | (interior?2:0) | (valid?4:0);
    }
    __syncthreads();
    for (int idx = tid; idx < 8192; idx += 256){
        int r = idx >> 7, c = idx & 127;
        float v = eb1[c] + eas[r*3]*ew1[c] + eas[r*3+1]*ew1[128+c] + eas[r*3+2]*ew1[256+c];
        hid[idx ^ ((r&7)<<3)] = f2bf(fmaxf(v, 0.f));
    }
    __syncthreads();
    int lane = tid&63, w = tid>>6, l16 = lane&15, q = lane>>4;
    int ar = 16*w + l16;
    f32x4 acc[8];
    #pragma unroll
    for (int nt=0; nt<8; nt++) acc[nt] = (f32x4){0.f,0.f,0.f,0.f};
    #pragma unroll
    for (int ks=0; ks<4; ks++){
        bf16x8 af = *(const bf16x8*)&hid[(ar*128 + ks*32 + q*8) ^ ((ar&7)<<3)];
        #pragma unroll
        for (int nt=0; nt<8; nt++){
            int n = nt*16 + l16;
            bf16x8 bfr = *(const bf16x8*)&wbs[(n*128 + ks*32 + q*8) ^ ((n&7)<<3)];
            acc[nt] = mfma16(af, bfr, acc[nt]);
        }
    }
    __syncthreads();   // GEMM reads of hid+wbs done
    {   // LN -> e-tile into hid (plain layout)
        float b2v[8], gv[8], bv[8];
        #pragma unroll
        for (int nt=0; nt<8; nt++){ int c = nt*16+l16; b2v[nt]=eb2[c]; gv[nt]=eg[c]; bv[nt]=ebe[c]; }
        #pragma unroll
        for (int reg=0; reg<4; reg++){
            float s=0.f, ss=0.f;
            #pragma unroll
            for (int nt=0; nt<8; nt++){ float v = acc[nt][reg] + b2v[nt]; acc[nt][reg]=v; s+=v; ss+=v*v; }
            #pragma unroll
            for (int m=1; m<16; m<<=1){ s += __shfl_xor(s,m); ss += __shfl_xor(ss,m); }
            float mean = s*(1.f/128.f);
            float rstd = __builtin_amdgcn_rsqf(ss*(1.f/128.f)-mean*mean+1e-5f);
            int rl = 16*w + 4*q + reg;
            #pragma unroll
            for (int nt=0; nt<8; nt++){
                int c = nt*16+l16;
                hid[rl*128 + c] = f2bf((acc[nt][reg]-mean)*rstd*gv[nt] + bv[nt]);
            }
        }
    }
    __syncthreads();
    for (int i = tid; i < 8192; i += 256) lag[i] = 0.f;   // zero agg slots (wbs dead)
    __syncthreads();
    // message + segmented LDS reduction
    for (int t = tid; t < 2048; t += 256){
        int r = t >> 5, cg = (t & 31) << 2;
        int fl = sfl[r];
        if (!(fl & 4)) continue;
        int s = ssrc[r];
        uint2 ev = *(const uint2*)&hid[r*128 + cg];
        float4 hv = *(const float4*)(h + (size_t)s*128 + cg);
        float m0 = fmaxf(hv.x + bf2f((u16)(ev.x & 0xFFFF)), 0.f);
        float m1 = fmaxf(hv.y + bf2f((u16)(ev.x >> 16)),   0.f);
        float m2 = fmaxf(hv.z + bf2f((u16)(ev.y & 0xFFFF)), 0.f);
        float m3 = fmaxf(hv.w + bf2f((u16)(ev.y >> 16)),   0.f);
        float* lp = lag + sslot[r]*128 + cg;
        atomicAdd(lp+0, m0); atomicAdd(lp+1, m1); atomicAdd(lp+2, m2); atomicAdd(lp+3, m3);
    }
    __syncthreads();
    // flush: one row per distinct dst; plain store if interior, atomic if boundary
    for (int t = tid; t < 2048; t += 256){
        int r = t >> 5, cg = (t & 31) << 2;
        int fl = sfl[r];
        if (!(fl & 1)) continue;
        float4 v = *(const float4*)&lag[r*128 + cg];
        float* gp = agg + (size_t)sdv[r]*128 + cg;
        if (fl & 2){ *(float4*)gp = v; }
        else { atomAddF(gp+0,v.x); atomAddF(gp+1,v.y); atomAddF(gp+2,v.z); atomAddF(gp+3,v.w); }
    }
}

// ---------------- GINE update ----------------
__global__ __launch_bounds__(256) void gine_update(
    float* h, const float* __restrict__ agg,
    const float* __restrict__ epsArr, int layer,
    const u16* __restrict__ w1T, const u16* __restrict__ w2T,
    const float* __restrict__ b1, const float* __restrict__ b2,
    const float* __restrict__ gam, const float* __restrict__ bet,
    int rows, int doRelu)
{
    __shared__ u16 wbs[128*128];
    __shared__ u16 hid[64*128];
    int tid = threadIdx.x, r0 = blockIdx.x*64;
    float epsv = 1.f + epsArr[layer];
    for (int i = tid; i < 8192; i += 256) ((uint32_t*)wbs)[i] = ((const uint32_t*)w1T)[i];
    __syncthreads();
    int lane = tid&63, w = tid>>6, l16 = lane&15, q = lane>>4;
    int ar = 16*w + l16;
    int arow = r0 + ar;
    int arc = arow < rows ? arow : rows-1;
    f32x4 acc[8];
    #pragma unroll
    for (int nt=0; nt<8; nt++) acc[nt] = (f32x4){0.f,0.f,0.f,0.f};
    #pragma unroll
    for (int ks=0; ks<4; ks++){
        const float4* hp = (const float4*)(h   + (size_t)arc*128 + ks*32 + q*8);
        const float4* ap = (const float4*)(agg + (size_t)arc*128 + ks*32 + q*8);
        float4 h0 = hp[0], h1 = hp[1], a0 = ap[0], a1 = ap[1];
        bf16x8 af;
        af[0]=(short)f2bf(fmaf(epsv,h0.x,a0.x)); af[1]=(short)f2bf(fmaf(epsv,h0.y,a0.y));
        af[2]=(short)f2bf(fmaf(epsv,h0.z,a0.z)); af[3]=(short)f2bf(fmaf(epsv,h0.w,a0.w));
        af[4]=(short)f2bf(fmaf(epsv,h1.x,a1.x)); af[5]=(short)f2bf(fmaf(epsv,h1.y,a1.y));
        af[6]=(short)f2bf(fmaf(epsv,h1.z,a1.z)); af[7]=(short)f2bf(fmaf(epsv,h1.w,a1.w));
        #pragma unroll
        for (int nt=0; nt<8; nt++){
            int n = nt*16 + l16;
            bf16x8 bfr = *(const bf16x8*)&wbs[(n*128 + ks*32 + q*8) ^ ((n&7)<<3)];
            acc[nt] = mfma16(af, bfr, acc[nt]);
        }
    }
    #pragma unroll
    for (int nt=0; nt<8; nt++){
        int c = nt*16 + l16; float b1v = b1[c];
        #pragma unroll
        for (int reg=0; reg<4; reg++){
            int rl = 16*w + 4*q + reg;
            hid[(rl*128 + c) ^ ((rl&7)<<3)] = f2bf(fmaxf(acc[nt][reg] + b1v, 0.f));
        }
    }
    __syncthreads();
    for (int i = tid; i < 8192; i += 256) ((uint32_t*)wbs)[i] = ((const uint32_t*)w2T)[i];
    __syncthreads();
    f32x4 a2[8];
    #pragma unroll
    for (int nt=0; nt<8; nt++) a2[nt] = (f32x4){0.f,0.f,0.f,0.f};
    #pragma unroll
    for (int ks=0; ks<4; ks++){
        bf16x8 af = *(const bf16x8*)&hid[(ar*128 + ks*32 + q*8) ^ ((ar&7)<<3)];
        #pragma unroll
        for (int nt=0; nt<8; nt++){
            int n = nt*16 + l16;
            bf16x8 bfr = *(const bf16x8*)&wbs[(n*128 + ks*32 + q*8) ^ ((n&7)<<3)];
            a2[nt] = mfma16(af, bfr, a2[nt]);
        }
    }
    float b2v[8], gv[8], bv[8];
    #pragma unroll
    for (int nt=0; nt<8; nt++){ int c = nt*16+l16; b2v[nt]=b2[c]; gv[nt]=gam[c]; bv[nt]=bet[c]; }
    #pragma unroll
    for (int reg=0; reg<4; reg++){
        float s=0.f, ss=0.f;
        #pragma unroll
        for (int nt=0; nt<8; nt++){ float v = a2[nt][reg] + b2v[nt]; a2[nt][reg]=v; s+=v; ss+=v*v; }
        #pragma unroll
        for (int m=1; m<16; m<<=1){ s += __shfl_xor(s,m); ss += __shfl_xor(ss,m); }
        float mean = s*(1.f/128.f);
        float rstd = __builtin_amdgcn_rsqf(ss*(1.f/128.f)-mean*mean+1e-5f);
        int row = r0 + 16*w + 4*q + reg;
        if (row < rows){
            #pragma unroll
            for (int nt=0; nt<8; nt++){
                int c = nt*16+l16;
                float o = (a2[nt][reg]-mean)*rstd*gv[nt] + bv[nt];
                if (doRelu) o = fmaxf(o, 0.f);
                h[(size_t)row*128 + c] = o;
            }
        }
    }
}

// ---------------- global mean pool (sorted batch -> per-block reduce) ----------------
__global__ __launch_bounds__(256) void pool2_kernel(
    const float* __restrict__ h, const int* __restrict__ batch,
    float* __restrict__ gsum, float* __restrict__ cnt, int N, int npb)
{
    __shared__ float lacc[16*128];
    __shared__ float lcnt[16];
    int tid = threadIdx.x;
    int n0 = blockIdx.x * npb;
    for (int i = tid; i < 2048; i += 256) lacc[i] = 0.f;
    if (tid < 16) lcnt[tid] = 0.f;
    __syncthreads();
    int rl = tid >> 5, cg = (tid & 31) << 2;
    int cur_b = -1; float4 acc = {0.f,0.f,0.f,0.f}; float c = 0.f;
    for (int k = rl; k < npb; k += 8){
        int n = n0 + k;
        if (n >= N) break;
        int b = batch[n];
        float4 hv = *(const float4*)(h + (size_t)n*128 + cg);
        if (b != cur_b){
            if (cur_b >= 0){
                float* lp = lacc + cur_b*128 + cg;
                atomicAdd(lp+0,acc.x); atomicAdd(lp+1,acc.y); atomicAdd(lp+2,acc.z); atomicAdd(lp+3,acc.w);
                if (cg == 0) atomicAdd(&lcnt[cur_b], c);
            }
            cur_b = b; acc = hv; c = 1.f;
        } else { acc.x+=hv.x; acc.y+=hv.y; acc.z+=hv.z; acc.w+=hv.w; c += 1.f; }
    }
    if (cur_b >= 0){
        float* lp = lacc + cur_b*128 + cg;
        atomicAdd(lp+0,acc.x); atomicAdd(lp+1,acc.y); atomicAdd(lp+2,acc.z); atomicAdd(lp+3,acc.w);
        if (cg == 0) atomicAdd(&lcnt[cur_b], c);
    }
    __syncthreads();
    int lastn = n0 + npb - 1; if (lastn > N-1) lastn = N-1;
    int firstn = n0 < N-1 ? n0 : N-1;
    int bmin = batch[firstn], bmax = batch[lastn];
    int rows = bmax - bmin + 1;
    for (int i = tid; i < rows*128; i += 256){
        int b = bmin + (i >> 7), cc = i & 127;
        float v = lacc[b*128 + cc];
        if (v != 0.f) atomAddF(gsum + b*128 + cc, v);
    }
    if (tid < rows){ float v = lcnt[bmin+tid]; if (v != 0.f) atomAddF(cnt + bmin + tid, v); }
}

__global__ __launch_bounds__(256) void gproc_kernel(
    const float* __restrict__ gsum, const float* __restrict__ cnt,
    const float* __restrict__ gw, const float* __restrict__ gb,
    const float* __restrict__ gg, const float* __restrict__ gbe,
    float* __restrict__ gfin)
{
    __shared__ float gm[2048];
    int tid = threadIdx.x;
    for (int i = tid; i < 2048; i += 256){ int b = i >> 7; gm[i] = gsum[i] / fmaxf(cnt[b], 1.f); }
    __syncthreads();
    int r = tid >> 4, m = tid & 15;
    float a[8];
    #pragma unroll
    for (int j=0;j<8;j++) a[j]=0.f;
    for (int k=0;k<128;k++){
        float gv = gm[r*128+k];
        #pragma unroll
        for (int j=0;j<8;j++) a[j] = fmaf(gv, gw[k*128 + m + 16*j], a[j]);
    }
    float s=0.f, ss=0.f;
    #pragma unroll
    for (int j=0;j<8;j++){ float v = fmaxf(a[j] + gb[m+16*j], 0.f); a[j]=v; s+=v; ss+=v*v; }
    #pragma unroll
    for (int msk=1; msk<16; msk<<=1){ s += __shfl_xor(s,msk); ss += __shfl_xor(ss,msk); }
    float mean = s*(1.f/128.f);
    float rstd = __builtin_amdgcn_rsqf(ss*(1.f/128.f)-mean*mean+1e-5f);
    #pragma unroll
    for (int j=0;j<8;j++){ int c = m+16*j; gfin[r*128+c] = (a[j]-mean)*rstd*gg[c] + gbe[c]; }
}

__global__ __launch_bounds__(256) void gc_kernel(
    const float* __restrict__ gfin, const float* __restrict__ ep_w1,
    const float* __restrict__ ep_b1, float* __restrict__ Gc)
{
    __shared__ float gs[2048];
    int tid = threadIdx.x;
    for (int i = tid; i < 2048; i += 256) gs[i] = gfin[i];
    __syncthreads();
    for (int o = tid; o < 16*256; o += 256){
        int r = o >> 8, n = o & 255;
        float a = ep_b1[n];
        for (int k = 0; k < 128; k++) a = fmaf(gs[r*128+k], ep_w1[(size_t)(256+k)*256 + n], a);
        Gc[o] = a;
    }
}

// HcS = h @ W1a, HcD = h @ W1b (bf16 [N][256])
__global__ __launch_bounds__(256) void hc_prep(
    const float* __restrict__ h, const u16* __restrict__ w1aT, const u16* __restrict__ w1bT,
    u16* __restrict__ hcS, u16* __restrict__ hcD, int rows)
{
    __shared__ u16 wbs[128*128];
    int tid = threadIdx.x, r0 = blockIdx.x*64;
    int lane = tid&63, w = tid>>6, l16 = lane&15, q = lane>>4;
    int arow = r0 + 16*w + l16;
    int arc = arow < rows ? arow : rows-1;
    bf16x8 afk[4];
    #pragma unroll
    for (int ks=0; ks<4; ks++){
        const float4* hp = (const float4*)(h + (size_t)arc*128 + ks*32 + q*8);
        float4 h0 = hp[0], h1 = hp[1];
        bf16x8 af;
        af[0]=(short)f2bf(h0.x); af[1]=(short)f2bf(h0.y); af[2]=(short)f2bf(h0.z); af[3]=(short)f2bf(h0.w);
        af[4]=(short)f2bf(h1.x); af[5]=(short)f2bf(h1.y); af[6]=(short)f2bf(h1.z); af[7]=(short)f2bf(h1.w);
        afk[ks] = af;
    }
    #pragma unroll
    for (int pass = 0; pass < 2; pass++){
        const u16* wt = pass ? w1bT : w1aT;
        f32x4 acc[16];
        #pragma unroll
        for (int i=0; i<16; i++) acc[i] = (f32x4){0.f,0.f,0.f,0.f};
        #pragma unroll
        for (int ch = 0; ch < 2; ch++){
            __syncthreads();
            for (int i = tid; i < 8192; i += 256) ((uint32_t*)wbs)[i] = ((const uint32_t*)wt)[ch*8192 + i];
            __syncthreads();
            #pragma unroll
            for (int ks=0; ks<4; ks++){
                #pragma unroll
                for (int nt=0; nt<8; nt++){
                    int n = nt*16 + l16;
                    bf16x8 bfr = *(const bf16x8*)&wbs[(n*128 + ks*32 + q*8) ^ ((n&7)<<3)];
                    acc[ch*8+nt] = mfma16(afk[ks], bfr, acc[ch*8+nt]);
                }
            }
        }
        u16* outp = pass ? hcD : hcS;
        #pragma unroll
        for (int reg=0; reg<4; reg++){
            int row = r0 + 16*w + 4*q + reg;
            if (row < rows){
                #pragma unroll
                for (int i=0; i<16; i++) outp[(size_t)row*256 + i*16 + l16] = f2bf(acc[i][reg]);
            }
        }
    }
}

// ---------------- edge predictor ----------------
__global__ __launch_bounds__(256) void pred_rc(
    const float* __restrict__ ea,
    const float* __restrict__ ew1, const float* __restrict__ eb1,
    const u16* __restrict__ ew2T, const float* __restrict__ eb2,
    const float* __restrict__ eg, const float* __restrict__ ebe,
    const int* __restrict__ src, const int* __restrict__ dst, const int* __restrict__ batch,
    const u16* __restrict__ hcS, const u16* __restrict__ hcD, const float* __restrict__ Gc,
    const u16* __restrict__ w1dT, const u16* __restrict__ epw2T,
    const float* __restrict__ b2, const float* __restrict__ w3, const float* __restrict__ b3,
    float* __restrict__ out, int E)
{
    __shared__ u16 wbs[64*128];
    __shared__ u16 s1t[64*256];
    __shared__ float eas[192];
    u16* het = s1t;
    int tid = threadIdx.x, r0 = blockIdx.x*64;
    int lane = tid&63, w = tid>>6, l16 = lane&15, q = lane>>4;
    int ar = 16*w + l16;

    if (tid < 192){ int rr = r0 + tid/3; int rc = rr < E ? rr : E-1; eas[tid] = ea[(size_t)rc*3 + (tid - (tid/3)*3)]; }
    int er[4], s4[4], d4[4], g4[4];
    #pragma unroll
    for (int reg=0; reg<4; reg++){
        int r = r0 + 16*w + 4*q + reg; er[reg] = r;
        int rc = r < E ? r : E-1;
        s4[reg] = src[rc]; d4[reg] = dst[rc]; g4[reg] = batch[s4[reg]];
    }
    __syncthreads();
    for (int idx = tid; idx < 8192; idx += 256){
        int r = idx >> 7, c = idx & 127;
        float v = eb1[c] + eas[r*3]*ew1[c] + eas[r*3+1]*ew1[128+c] + eas[r*3+2]*ew1[256+c];
        het[idx ^ ((r&7)<<3)] = f2bf(fmaxf(v, 0.f));
    }
    f32x4 eac[8];
    #pragma unroll
    for (int i=0;i<8;i++) eac[i] = (f32x4){0.f,0.f,0.f,0.f};
    #pragma unroll
    for (int ch=0; ch<2; ch++){
        __syncthreads();
        for (int i=tid; i<4096; i+=256) ((uint32_t*)wbs)[i] = ((const uint32_t*)ew2T)[ch*4096 + i];
        __syncthreads();
        #pragma unroll
        for (int ks=0; ks<4; ks++){
            bf16x8 af = *(const bf16x8*)&het[(ar*128 + ks*32 + q*8) ^ ((ar&7)<<3)];
            #pragma unroll
            for (int nt=0; nt<4; nt++){
                int n = nt*16 + l16;
                bf16x8 bfr = *(const bf16x8*)&wbs[(n*128 + ks*32 + q*8) ^ ((n&7)<<3)];
                eac[ch*4+nt] = mfma16(af, bfr, eac[ch*4+nt]);
            }
        }
    }
    __syncthreads();
    {
        float b2v[8], gv[8], bv[8];
        #pragma unroll
        for (int i=0;i<8;i++){ int c=i*16+l16; b2v[i]=eb2[c]; gv[i]=eg[c]; bv[i]=ebe[c]; }
        #pragma unroll
        for (int reg=0; reg<4; reg++){
            float s=0.f, ss=0.f;
            #pragma unroll
            for (int i=0;i<8;i++){ float v = eac[i][reg]+b2v[i]; eac[i][reg]=v; s+=v; ss+=v*v; }
            #pragma unroll
            for (int m=1;m<16;m<<=1){ s+=__shfl_xor(s,m); ss+=__shfl_xor(ss,m); }
            float mean = s*(1.f/128.f);
            float rstd = __builtin_amdgcn_rsqf(ss*(1.f/128.f)-mean*mean+1e-5f);
            int rl = 16*w + 4*q + reg;
            #pragma unroll
            for (int i=0;i<8;i++){
                int c = i*16+l16;
                het[(rl*128 + c) ^ ((rl&7)<<3)] = f2bf((eac[i][reg]-mean)*rstd*gv[i]+bv[i]);
            }
        }
    }
    f32x4 acc[16];
    #pragma unroll
    for (int i=0;i<16;i++) acc[i] = (f32x4){0.f,0.f,0.f,0.f};
    #pragma unroll
    for (int ch=0; ch<4; ch++){
        __syncthreads();
        for (int i=tid; i<4096; i+=256) ((uint32_t*)wbs)[i] = ((const uint32_t*)w1dT)[ch*4096 + i];
        __syncthreads();
        #pragma unroll
        for (int ks=0; ks<4; ks++){
            bf16x8 af = *(const bf16x8*)&het[(ar*128 + ks*32 + q*8) ^ ((ar&7)<<3)];
            #pragma unroll
            for (int nt=0; nt<4; nt++){
                int n = nt*16 + l16;
                bf16x8 bfr = *(const bf16x8*)&wbs[(n*128 + ks*32 + q*8) ^ ((n&7)<<3)];
                acc[ch*4+nt] = mfma16(af, bfr, acc[ch*4+nt]);
            }
        }
    }
    __syncthreads();
    #pragma unroll
    for (int i=0; i<16; i++){
        int c = i*16 + l16;
        #pragma unroll
        for (int reg=0; reg<4; reg++){
            float t = acc[i][reg]
                    + bf2f(hcS[(size_t)s4[reg]*256 + c])
                    + bf2f(hcD[(size_t)d4[reg]*256 + c])
                    + Gc[g4[reg]*256 + c];
            int rl = 16*w + 4*q + reg;
            s1t[(rl*256 + c) ^ ((rl&7)<<3)] = f2bf(fast_tanh(t));
        }
    }
    f32x4 a2[8];
    #pragma unroll
    for (int i=0;i<8;i++) a2[i] = (f32x4){0.f,0.f,0.f,0.f};
    #pragma unroll
    for (int kh=0; kh<2; kh++){
        #pragma unroll
        for (int nh=0; nh<2; nh++){
            __syncthreads();
            for (int i=tid; i<4096; i+=256)
                ((uint32_t*)wbs)[i] = ((const uint32_t*)epw2T)[(nh*64 + (i>>6))*128 + kh*64 + (i&63)];
            __syncthreads();
            #pragma unroll
            for (int ks=0; ks<4; ks++){
                bf16x8 af = *(const bf16x8*)&s1t[(ar*256 + kh*128 + ks*32 + q*8) ^ ((ar&7)<<3)];
                #pragma unroll
                for (int nt=0; nt<4; nt++){
                    int nl = nt*16 + l16;
                    bf16x8 bfr = *(const bf16x8*)&wbs[(nl*128 + ks*32 + q*8) ^ ((nl&7)<<3)];
                    a2[nh*4+nt] = mfma16(af, bfr, a2[nh*4+nt]);
                }
            }
        }
    }
    float p[4] = {0.f,0.f,0.f,0.f};
    #pragma unroll
    for (int i=0;i<8;i++){
        int c = i*16 + l16;
        float b2v = b2[c], w3v = w3[c];
        #pragma unroll
        for (int reg=0;reg<4;reg++){
            float v = fast_tanh(a2[i][reg] + b2v);
            p[reg] = fmaf(v, w3v, p[reg]);
        }
    }
    float b3v = b3[0];
    #pragma unroll
    for (int reg=0;reg<4;reg++){
        float pv = p[reg];
        #pragma unroll
        for (int m=1;m<16;m<<=1) pv += __shfl_xor(pv,m);
        if (l16==0 && er[reg] < E) out[er[reg]] = fast_sigmoid(pv + b3v);
    }
}

extern "C" void kernel_launch(void* const* d_in, const int* in_sizes, int n_in,
                              void* d_out, int out_size, void* d_ws, size_t ws_size,
                              hipStream_t stream)
{
    if (n_in < 33){ diag_kernel<<<1,64,0,stream>>>((float*)d_out, 2.0e6f); return; }
    const float* x      = (const float*)d_in[0];
    const float* ea     = (const float*)d_in[1];
    const int*   eidx   = (const int*)  d_in[2];
    const int*   batch  = (const int*)  d_in[3];
    const float* ne_w1  = (const float*)d_in[4];
    const float* ne_b1  = (const float*)d_in[5];
    const float* ne_w2  = (const float*)d_in[6];
    const float* ne_b2  = (const float*)d_in[7];
    const float* ne_g   = (const float*)d_in[8];
    const float* ne_be  = (const float*)d_in[9];
    const float* ee_w1  = (const float*)d_in[10];
    const float* ee_b1  = (const float*)d_in[11];
    const float* ee_w2  = (const float*)d_in[12];
    const float* ee_b2  = (const float*)d_in[13];
    const float* ee_g   = (const float*)d_in[14];
    const float* ee_be  = (const float*)d_in[15];
    const float* gin_eps= (const float*)d_in[16];
    const float* gin_w1 = (const float*)d_in[17];
    const float* gin_b1 = (const float*)d_in[18];
    const float* gin_w2 = (const float*)d_in[19];
    const float* gin_b2 = (const float*)d_in[20];
    const float* gin_g  = (const float*)d_in[21];
    const float* gin_be = (const float*)d_in[22];
    const float* gp_w   = (const float*)d_in[23];
    const float* gp_b   = (const float*)d_in[24];
    const float* gp_g   = (const float*)d_in[25];
    const float* gp_be  = (const float*)d_in[26];
    const float* ep_w1  = (const float*)d_in[27];
    const float* ep_b1  = (const float*)d_in[28];
    const float* ep_w2  = (const float*)d_in[29];
    const float* ep_b2  = (const float*)d_in[30];
    const float* ep_w3  = (const float*)d_in[31];
    const float* ep_b3  = (const float*)d_in[32];

    int N = in_sizes[0] / 3;
    int E = in_sizes[1] / 3;
    const int* srcI = eidx;
    const int* dstI = eidx + E;

    char* ws = (char*)d_ws;
    size_t off = 0;
    auto alloc = [&](size_t bytes) -> void* {
        void* p = ws + off; off += (bytes + 255) & ~(size_t)255; return p;
    };
    float* h     = (float*)alloc((size_t)N*512);
    char*  R1    = (char*) alloc((size_t)N*512);   // agg (f32 N*128) then hcS (bf16 N*256)
    u16*   hcD   = (u16*)  alloc((size_t)N*512);
    int*   deg   = (int*)  alloc((size_t)N*4);
    int*   curp  = (int*)  alloc((size_t)N*4);
    int*   src_s = (int*)  alloc((size_t)E*4);
    int*   dst_s = (int*)  alloc((size_t)E*4);
    float* ea_s  = (float*)alloc((size_t)E*12);
    float* gsum  = (float*)alloc((2048+64)*4);
    float* cnt   = gsum + 2048;
    float* gfin  = (float*)alloc(2048*4);
    float* Gc    = (float*)alloc(16*256*4);
    u16* ne_w2T = (u16*)alloc(16384*2);
    u16* ee_w2T = (u16*)alloc(16384*2);
    u16* gw1T0  = (u16*)alloc(16384*2);
    u16* gw1T1  = (u16*)alloc(16384*2);
    u16* gw2T0  = (u16*)alloc(16384*2);
    u16* gw2T1  = (u16*)alloc(16384*2);
    u16* w1aT   = (u16*)alloc(32768*2);
    u16* w1bT   = (u16*)alloc(32768*2);
    u16* w1dT   = (u16*)alloc(32768*2);
    u16* epw2T  = (u16*)alloc(32768*2);
    if (off > ws_size){
        diag_kernel<<<1,64,0,stream>>>((float*)d_out, 1.0e6f + (float)(ws_size >> 20));
        return;
    }
    float* agg = (float*)R1;
    u16*   hcS = (u16*)R1;

    // weight prep
    prep_wT<<<64, 256, 0, stream>>>(ne_w2, 128, ne_w2T, 128, 128);
    prep_wT<<<64, 256, 0, stream>>>(ee_w2, 128, ee_w2T, 128, 128);
    prep_wT<<<64, 256, 0, stream>>>(gin_w1,           128, gw1T0, 128, 128);
    prep_wT<<<64, 256, 0, stream>>>(gin_w1 + 128*128, 128, gw1T1, 128, 128);
    prep_wT<<<64, 256, 0, stream>>>(gin_w2,           128, gw2T0, 128, 128);
    prep_wT<<<64, 256, 0, stream>>>(gin_w2 + 128*128, 128, gw2T1, 128, 128);
    prep_wT<<<128,256, 0, stream>>>(ep_w1,            256, w1aT, 128, 256);
    prep_wT<<<128,256, 0, stream>>>(ep_w1 + 128*256,  256, w1bT, 128, 256);
    prep_wT<<<128,256, 0, stream>>>(ep_w1 + 384*256,  256, w1dT, 128, 256);
    prep_wT<<<128,256, 0, stream>>>(ep_w2,            128, epw2T, 256, 128);

    // CSR-by-dst build
    hipMemsetAsync(deg, 0, (size_t)N*4, stream);
    hist_kernel<<<(E+255)/256, 256, 0, stream>>>(dstI, deg, E);
    scan_kernel<<<1, 1024, 0, stream>>>(deg, curp, N);
    scatter_kernel<<<(E+255)/256, 256, 0, stream>>>(srcI, dstI, ea, curp, src_s, dst_s, ea_s, E);

    int nbN = (N + 63) / 64;
    int nbE = (E + 63) / 64;
    enc_kernel<<<nbN, 256, 0, stream>>>(x, N, ne_w1, ne_b1, ne_w2T, ne_b2, ne_g, ne_be, h);

    for (int l = 0; l < 2; l++){
        hipMemsetAsync(agg, 0, (size_t)N*512, stream);
        msg_sorted<<<nbE, 256, 0, stream>>>(ea_s, src_s, dst_s,
                                            ee_w1, ee_b1, ee_w2T, ee_b2, ee_g, ee_be,
                                            h, agg, E);
        gine_update<<<nbN, 256, 0, stream>>>(h, agg, gin_eps, l,
            l ? gw1T1 : gw1T0, l ? gw2T1 : gw2T0,
            gin_b1 + l*128, gin_b2 + l*128, gin_g + l*128, gin_be + l*128,
            N, l == 0 ? 1 : 0);
    }

    hipMemsetAsync(gsum, 0, (2048 + 16) * 4, stream);
    int npb = 512;
    pool2_kernel<<<(N + npb - 1)/npb, 256, 0, stream>>>(h, batch, gsum, cnt, N, npb);
    gproc_kernel<<<1, 256, 0, stream>>>(gsum, cnt, gp_w, gp_b, gp_g, gp_be, gfin);
    gc_kernel<<<1, 256, 0, stream>>>(gfin, ep_w1, ep_b1, Gc);
    hc_prep<<<nbN, 256, 0, stream>>>(h, w1aT, w1bT, hcS, hcD, N);
    pred_rc<<<nbE, 256, 0, stream>>>(ea, ee_w1, ee_b1, ee_w2T, ee_b2, ee_g, ee_be,
                                     srcI, dstI, batch, hcS, hcD, Gc,
                                     w1dT, epw2T, ep_b2, ep_w3, ep_b3,
                                     (float*)d_out, E);
}